// Round 6
// baseline (166.955 us; speedup 1.0000x reference)
//
#include <hip/hip_runtime.h>

#define NB 128
#define NS 8192
#define NC 64
#define NL (NS / NC)          // 128 steps per chunk
#define GRID (NB * NC / 16)   // 512 blocks (16 threads per chunk column-group)

#define LOG2E 1.4426950408889634f
#define HLOG2PI 0.918938533204672742f
#define LN2 0.69314718055994531f

// fast-phase23 LDS layout
#define ROWS 20          // padded leading dim
#define UNIT 640         // dual unit: R[16x20] + T[16x20]
#define SLOT 320

__device__ __forceinline__ float fexp2(float x) { return __builtin_amdgcn_exp2f(x); }
__device__ __forceinline__ float flog2(float x) { return __builtin_amdgcn_logf(x); }

__device__ __forceinline__ float gsum16(float v) {
    v += __shfl_xor(v, 1, 16);
    v += __shfl_xor(v, 2, 16);
    v += __shfl_xor(v, 4, 16);
    v += __shfl_xor(v, 8, 16);
    return v;
}
__device__ __forceinline__ float gmax16(float v) {
    v = fmaxf(v, __shfl_xor(v, 1, 16));
    v = fmaxf(v, __shfl_xor(v, 2, 16));
    v = fmaxf(v, __shfl_xor(v, 4, 16));
    v = fmaxf(v, __shfl_xor(v, 8, 16));
    return v;
}

template <int K>
__device__ __forceinline__ int rotk(int x) {
    return __builtin_amdgcn_mov_dpp(x, 0x120 + K, 0xF, 0xF, false);
}

// One HMM step in rotated-W layout (PROVEN round-3 form: per-step rescale inside).
__device__ __forceinline__ void step_fn(float (&W)[16], int& ilog, float xx,
                                        float A2, float B2, float C2) {
    const float amb = 0.9f - 0.1f / 15.0f;
    const float bco = 0.1f / 15.0f;
    float s0 = (W[0] + W[1]) + (W[2] + W[3]);
    float s1 = (W[4] + W[5]) + (W[6] + W[7]);
    float s2 = (W[8] + W[9]) + (W[10] + W[11]);
    float s3 = (W[12] + W[13]) + (W[14] + W[15]);
    float T = (s0 + s1) + (s2 + s3);
    if (T < 0x1p-40f) {                    // T only shrinks (max lik < 0.6)
#pragma unroll
        for (int k = 0; k < 16; ++k) W[k] *= 0x1p80f;
        T *= 0x1p80f;
        ilog -= 80;
    }
    float myl = fexp2(fmaf(xx, fmaf(xx, A2, B2), C2));   // ONE exp per lane
    int mi = __float_as_int(myl);
    float bT = bco * T;
    W[0]  = fmaf(amb, W[0],  bT) * myl;
    W[1]  = fmaf(amb, W[1],  bT) * __int_as_float(rotk<1>(mi));
    W[2]  = fmaf(amb, W[2],  bT) * __int_as_float(rotk<2>(mi));
    W[3]  = fmaf(amb, W[3],  bT) * __int_as_float(rotk<3>(mi));
    W[4]  = fmaf(amb, W[4],  bT) * __int_as_float(rotk<4>(mi));
    W[5]  = fmaf(amb, W[5],  bT) * __int_as_float(rotk<5>(mi));
    W[6]  = fmaf(amb, W[6],  bT) * __int_as_float(rotk<6>(mi));
    W[7]  = fmaf(amb, W[7],  bT) * __int_as_float(rotk<7>(mi));
    W[8]  = fmaf(amb, W[8],  bT) * __int_as_float(rotk<8>(mi));
    W[9]  = fmaf(amb, W[9],  bT) * __int_as_float(rotk<9>(mi));
    W[10] = fmaf(amb, W[10], bT) * __int_as_float(rotk<10>(mi));
    W[11] = fmaf(amb, W[11], bT) * __int_as_float(rotk<11>(mi));
    W[12] = fmaf(amb, W[12], bT) * __int_as_float(rotk<12>(mi));
    W[13] = fmaf(amb, W[13], bT) * __int_as_float(rotk<13>(mi));
    W[14] = fmaf(amb, W[14], bT) * __int_as_float(rotk<14>(mi));
    W[15] = fmaf(amb, W[15], bT) * __int_as_float(rotk<15>(mi));
}

// P = Mb * Ma, one product per wave; lane (a=lane>>3, c=lane&7) -> 2x2 tile.
// All operand reads ds_read_b128 (rows from R-layout, cols from padded T-layout).
__device__ __forceinline__ void mat16_mul(float* dR, float* dT,
                                          const float* MbR, const float* MaT,
                                          int lane) {
    int a = lane >> 3;
    int c = lane & 7;
    float b0[16], b1[16], a0[16], a1[16];
    const float4* pb0 = (const float4*)(MbR + (2 * a) * ROWS);
    const float4* pb1 = (const float4*)(MbR + (2 * a + 1) * ROWS);
    const float4* pa0 = (const float4*)(MaT + (2 * c) * ROWS);
    const float4* pa1 = (const float4*)(MaT + (2 * c + 1) * ROWS);
#pragma unroll
    for (int q = 0; q < 4; ++q) {
        *(float4*)&b0[4 * q] = pb0[q];
        *(float4*)&b1[4 * q] = pb1[q];
        *(float4*)&a0[4 * q] = pa0[q];
        *(float4*)&a1[4 * q] = pa1[q];
    }
    float c00 = 0.f, c01 = 0.f, c10 = 0.f, c11 = 0.f;
#pragma unroll
    for (int k = 0; k < 16; ++k) {
        c00 = fmaf(b0[k], a0[k], c00);
        c01 = fmaf(b0[k], a1[k], c01);
        c10 = fmaf(b1[k], a0[k], c10);
        c11 = fmaf(b1[k], a1[k], c11);
    }
    *(float2*)(dR + (2 * a) * ROWS + 2 * c)     = make_float2(c00, c01);
    *(float2*)(dR + (2 * a + 1) * ROWS + 2 * c) = make_float2(c10, c11);
    if (dT) {
        *(float2*)(dT + (2 * c) * ROWS + 2 * a)     = make_float2(c00, c10);
        *(float2*)(dT + (2 * c + 1) * ROWS + 2 * a) = make_float2(c01, c11);
    }
}

// Single fused kernel: phase1 (all 512 blocks) -> device barrier -> phase23
// (blocks 0..127, one per b). Barrier counter bar[0] and reference bar[1] start
// from the SAME uniform ws fill (harness poisons 0xAA), so target = bar[1]+GRID
// works for any uniform initial fill, every launch. All 512 blocks co-resident:
// LDS 51.2KB -> 3 blocks/CU capacity (768 >= 512).
__global__ __launch_bounds__(256, 3) void hmm_fused(const float* __restrict__ obvs,
                                                    const float* __restrict__ mu,
                                                    const float* __restrict__ log_sigma,
                                                    const float* __restrict__ prior_logits,
                                                    float* __restrict__ wsW,
                                                    float* __restrict__ wsM,
                                                    unsigned* __restrict__ bar,
                                                    float* __restrict__ out) {
    __shared__ float smem[12800];   // 51,200 B: stage(8x640) + scr(8x640) + resB(8x320)
    float* stage = smem;
    float* scr   = smem + 5120;
    float* resB  = smem + 10240;

    // ---------------- phase 1 (proven round-3 math) ----------------
    {
        int tidg = blockIdx.x * 256 + threadIdx.x;
        if (tidg == 0) out[0] = 0.0f;          // zeroed pre-barrier, fenced by release
        int r = threadIdx.x & 15;
        int g = tidg >> 4;                     // g = b*NC + c
        int b = g >> 6;
        int c = g & (NC - 1);

        float ls = log_sigma[r];
        float mk = mu[r];
        float iv = fexp2(-2.0f * LOG2E * ls);
        float A2 = -0.5f * LOG2E * iv;
        float B2 = LOG2E * mk * iv;
        float C2 = LOG2E * (-0.5f * mk * mk * iv - ls - HLOG2PI);

        float W[16];
#pragma unroll
        for (int k = 0; k < 16; ++k) W[k] = (k == 0) ? 1.0f : 0.0f;
        int ilog = 0;

        const float4* ob4 = (const float4*)(obvs + (long)b * NS) + c * (NL / 4);
        float4 xv = ob4[0];
        for (int m = 0; m < NL / 4; ++m) {
            float4 xnext = ob4[(m + 1) & (NL / 4 - 1)];
            if (m | c) step_fn(W, ilog, xv.x, A2, B2, C2);  // skip t=0 (epilogue init)
            step_fn(W, ilog, xv.y, A2, B2, C2);
            step_fn(W, ilog, xv.z, A2, B2, C2);
            step_fn(W, ilog, xv.w, A2, B2, C2);
            xv = xnext;
        }

        int sid[16];
        sid[0] = r;
        sid[1]  = rotk<1>(r);   sid[2]  = rotk<2>(r);   sid[3]  = rotk<3>(r);
        sid[4]  = rotk<4>(r);   sid[5]  = rotk<5>(r);   sid[6]  = rotk<6>(r);
        sid[7]  = rotk<7>(r);   sid[8]  = rotk<8>(r);   sid[9]  = rotk<9>(r);
        sid[10] = rotk<10>(r);  sid[11] = rotk<11>(r);  sid[12] = rotk<12>(r);
        sid[13] = rotk<13>(r);  sid[14] = rotk<14>(r);  sid[15] = rotk<15>(r);

        float s0 = (W[0] + W[1]) + (W[2] + W[3]);
        float s1 = (W[4] + W[5]) + (W[6] + W[7]);
        float s2 = (W[8] + W[9]) + (W[10] + W[11]);
        float s3 = (W[12] + W[13]) + (W[14] + W[15]);
        float Tf = (s0 + s1) + (s2 + s3);
        float lg = (float)ilog + flog2(Tf);
        float mx = gmax16(lg);
        float sc = fexp2((float)ilog - mx);
        float* dst = wsW + (long)g * 256 + r;   // M[j][r] at j*16+r
#pragma unroll
        for (int k = 0; k < 16; ++k) dst[sid[k] * 16] = W[k] * sc;
        if (r == 0) wsM[g] = mx;
    }

    // ---------------- device-scope barrier ----------------
    __syncthreads();                            // drains all waves' stores (vmcnt 0)
    if (threadIdx.x == 0) {
        __threadfence();                        // release to device scope
        atomicAdd(&bar[0], 1u);
    }
    if (blockIdx.x >= NB) return;               // blocks 128..511 done
    if (threadIdx.x == 0) {
        unsigned base = __hip_atomic_load(&bar[1], __ATOMIC_RELAXED, __HIP_MEMORY_SCOPE_AGENT);
        while ((unsigned)(__hip_atomic_load(&bar[0], __ATOMIC_ACQUIRE,
                                            __HIP_MEMORY_SCOPE_AGENT) - base) < (unsigned)GRID)
            __builtin_amdgcn_s_sleep(2);
        __threadfence();                        // acquire
    }
    __syncthreads();

    // ---------------- phase 2+3 (wave-per-product, b128 LDS reads) ----------------
    int bb = blockIdx.x;
    int tid = threadIdx.x;
    int wid = tid >> 6;
    int lane = tid & 63;

    for (int rd = 0; rd < 8; ++rd) {
        // stage 8 chunk matrices in dual (row + padded-transpose) layout
        const float4* src = (const float4*)(wsW + ((long)bb * NC + rd * 8) * 256);
#pragma unroll
        for (int q = 0; q < 2; ++q) {
            int f = tid + q * 256;
            float4 v = src[f];
            int m = f >> 6, idx = f & 63, j = idx >> 2, kq = idx & 3;
            *(float4*)(stage + m * UNIT + j * ROWS + kq * 4) = v;
            float* Tb = stage + m * UNIT + SLOT;
            Tb[(4 * kq + 0) * ROWS + j] = v.x;
            Tb[(4 * kq + 1) * ROWS + j] = v.y;
            Tb[(4 * kq + 2) * ROWS + j] = v.z;
            Tb[(4 * kq + 3) * ROWS + j] = v.w;
        }
        __syncthreads();
        // in-round tree 8 -> 4 -> 2 -> 1 (later * earlier)
        if (wid < 4)
            mat16_mul(scr + wid * UNIT, scr + wid * UNIT + SLOT,
                      stage + (2 * wid + 1) * UNIT, stage + (2 * wid) * UNIT + SLOT, lane);
        __syncthreads();
        if (wid < 2)
            mat16_mul(scr + (4 + wid) * UNIT, scr + (4 + wid) * UNIT + SLOT,
                      scr + (2 * wid + 1) * UNIT, scr + (2 * wid) * UNIT + SLOT, lane);
        __syncthreads();
        if (wid == 0)
            mat16_mul(resB + rd * SLOT, nullptr,
                      scr + 5 * UNIT, scr + 4 * UNIT + SLOT, lane);
        __syncthreads();
    }

    // transposes of the 8 round-results into stage[m*SLOT]
    for (int e = tid; e < 8 * 256; e += 256) {
        int m = e >> 8, idx = e & 255, j = idx >> 4, r = idx & 15;
        stage[m * SLOT + r * ROWS + j] = resB[m * SLOT + j * ROWS + r];
    }
    __syncthreads();

    // final tree 8 -> 4 -> 2 -> 1
    for (int i = wid; i < 4; i += 4)
        mat16_mul(scr + i * UNIT, scr + i * UNIT + SLOT,
                  resB + (2 * i + 1) * SLOT, stage + (2 * i) * SLOT, lane);
    __syncthreads();
    float* cur = scr;
    float* oth = stage;
    int n = 4;
    while (n > 1) {
        n >>= 1;
        for (int i = wid; i < n; i += 4)
            mat16_mul(oth + i * UNIT, oth + i * UNIT + SLOT,
                      cur + (2 * i + 1) * UNIT, cur + (2 * i) * UNIT + SLOT, lane);
        __syncthreads();
        float* t = cur; cur = oth; oth = t;
    }
    // final combined matrix rows at cur[j*ROWS + k]

    // epilogue: init vector, apply matrix, logsumexp, accumulate
    if (tid < 16) {
        int jj = tid;
        float ls = log_sigma[jj];
        float mk = mu[jj];
        float iv = fexp2(-2.0f * LOG2E * ls);
        float A2 = -0.5f * LOG2E * iv;
        float B2 = LOG2E * mk * iv;
        float C2 = LOG2E * (-0.5f * mk * mk * iv - ls - HLOG2PI);
        float x = obvs[(long)bb * NS];                   // t = 0
        float e = fexp2(LOG2E * prior_logits[jj]);
        float Z = gsum16(e);
        float p0 = fexp2(fmaf(x, fmaf(x, A2, B2), C2)) * e;
        const float* Mrow = cur + jj * ROWS;
        float mr[16];
        *(float4*)&mr[0]  = ((const float4*)Mrow)[0];
        *(float4*)&mr[4]  = ((const float4*)Mrow)[1];
        *(float4*)&mr[8]  = ((const float4*)Mrow)[2];
        *(float4*)&mr[12] = ((const float4*)Mrow)[3];
        float q = 0.0f;
#pragma unroll
        for (int rr = 0; rr < 16; ++rr) q = fmaf(mr[rr], __shfl(p0, rr, 16), q);
        float Tq = gsum16(q);
        const float* pm = wsM + bb * NC + jj * 4;
        float msum = gsum16(pm[0] + pm[1] + pm[2] + pm[3]);
        if (jj == 0) {
            float res = (flog2(Tq) - flog2(Z) + msum) * LN2;
            atomicAdd(out, res);
        }
    }
}

extern "C" void kernel_launch(void* const* d_in, const int* in_sizes, int n_in,
                              void* d_out, int out_size, void* d_ws, size_t ws_size,
                              hipStream_t stream) {
    const float* obvs = (const float*)d_in[0];
    const float* mu = (const float*)d_in[1];
    const float* log_sigma = (const float*)d_in[2];
    const float* prior_logits = (const float*)d_in[3];
    float* out = (float*)d_out;

    float* wsW = (float*)d_ws;                          // NB*NC*256 floats = 8.39 MB
    float* wsM = wsW + (size_t)NB * NC * 256;           // 8192 floats
    unsigned* bar = (unsigned*)(wsM + (size_t)NB * NC); // bar[0]=counter, bar[1]=ref

    hmm_fused<<<dim3(GRID), dim3(256), 0, stream>>>(obvs, mu, log_sigma, prior_logits,
                                                    wsW, wsM, bar, out);
}

// Round 8
// 117.382 us; speedup vs baseline: 1.4223x; 1.4223x over previous
//
#include <hip/hip_runtime.h>

#define NB 128
#define NS 8192
#define NC 64
#define NL (NS / NC)          // 128 steps per chunk
#define M4 (NL / 4)           // 32 float4 groups

#define LOG2E 1.4426950408889634f
#define HLOG2PI 0.918938533204672742f
#define LN2 0.69314718055994531f

// phase23 LDS layout (round-6-proven)
#define ROWS 20          // padded leading dim
#define UNIT 640         // dual unit: R[16x20] + T[16x20]
#define SLOT 320

__device__ __forceinline__ float fexp2(float x) { return __builtin_amdgcn_exp2f(x); }
__device__ __forceinline__ float flog2(float x) { return __builtin_amdgcn_logf(x); }

__device__ __forceinline__ float gsum16(float v) {
    v += __shfl_xor(v, 1, 16);
    v += __shfl_xor(v, 2, 16);
    v += __shfl_xor(v, 4, 16);
    v += __shfl_xor(v, 8, 16);
    return v;
}
__device__ __forceinline__ float gmax16(float v) {
    v = fmaxf(v, __shfl_xor(v, 1, 16));
    v = fmaxf(v, __shfl_xor(v, 2, 16));
    v = fmaxf(v, __shfl_xor(v, 4, 16));
    v = fmaxf(v, __shfl_xor(v, 8, 16));
    return v;
}

template <int K>
__device__ __forceinline__ int rotk(int x) {
    return __builtin_amdgcn_mov_dpp(x, 0x120 + K, 0xF, 0xF, false);
}

// One HMM step in rotated-W layout; takes current colsum T, returns new colsum.
// No rescale logic inside (hoisted to per-4-step renorm).
__device__ __forceinline__ float step2(float (&W)[16], float T, float xx,
                                       float A2, float B2, float C2) {
    const float amb = 0.9f - 0.1f / 15.0f;
    const float bco = 0.1f / 15.0f;
    float myl = fexp2(fmaf(xx, fmaf(xx, A2, B2), C2));   // ONE exp per lane
    int mi = __float_as_int(myl);
    float bT = bco * T;
    W[0]  = fmaf(amb, W[0],  bT) * myl;
    W[1]  = fmaf(amb, W[1],  bT) * __int_as_float(rotk<1>(mi));
    W[2]  = fmaf(amb, W[2],  bT) * __int_as_float(rotk<2>(mi));
    W[3]  = fmaf(amb, W[3],  bT) * __int_as_float(rotk<3>(mi));
    W[4]  = fmaf(amb, W[4],  bT) * __int_as_float(rotk<4>(mi));
    W[5]  = fmaf(amb, W[5],  bT) * __int_as_float(rotk<5>(mi));
    W[6]  = fmaf(amb, W[6],  bT) * __int_as_float(rotk<6>(mi));
    W[7]  = fmaf(amb, W[7],  bT) * __int_as_float(rotk<7>(mi));
    W[8]  = fmaf(amb, W[8],  bT) * __int_as_float(rotk<8>(mi));
    W[9]  = fmaf(amb, W[9],  bT) * __int_as_float(rotk<9>(mi));
    W[10] = fmaf(amb, W[10], bT) * __int_as_float(rotk<10>(mi));
    W[11] = fmaf(amb, W[11], bT) * __int_as_float(rotk<11>(mi));
    W[12] = fmaf(amb, W[12], bT) * __int_as_float(rotk<12>(mi));
    W[13] = fmaf(amb, W[13], bT) * __int_as_float(rotk<13>(mi));
    W[14] = fmaf(amb, W[14], bT) * __int_as_float(rotk<14>(mi));
    W[15] = fmaf(amb, W[15], bT) * __int_as_float(rotk<15>(mi));
    float s0 = (W[0] + W[1]) + (W[2] + W[3]);
    float s1 = (W[4] + W[5]) + (W[6] + W[7]);
    float s2 = (W[8] + W[9]) + (W[10] + W[11]);
    float s3 = (W[12] + W[13]) + (W[14] + W[15]);
    return (s0 + s1) + (s2 + s3);
}

// Phase 1 (round-4-proven skeleton: nc=64, fp32 store): thread (b, chunk c,
// column r) evolves basis e_r. SUSPECT UNDER TEST: branchless per-4-step
// exponent renorm (strip T's exponent into ilog) with a te==0 guard so an
// (impossible-per-data) T underflow cannot cause a 2^127 runaway.
__global__ __launch_bounds__(256, 4) void hmm_phase1(const float* __restrict__ obvs,
                                                     const float* __restrict__ mu,
                                                     const float* __restrict__ log_sigma,
                                                     float* __restrict__ wsW,
                                                     float* __restrict__ wsM,
                                                     float* __restrict__ out) {
    int tid = blockIdx.x * blockDim.x + threadIdx.x;
    if (tid == 0) out[0] = 0.0f;           // phase23 atomicAdds after this dispatch
    int r = tid & 15;
    int g = tid >> 4;                      // g = b*NC + c
    int b = g >> 6;
    int c = g & (NC - 1);

    float ls = log_sigma[r];
    float mk = mu[r];
    float iv = fexp2(-2.0f * LOG2E * ls);
    float A2 = -0.5f * LOG2E * iv;
    float B2 = LOG2E * mk * iv;
    float C2 = LOG2E * (-0.5f * mk * mk * iv - ls - HLOG2PI);

    float W[16];
#pragma unroll
    for (int k = 0; k < 16; ++k) W[k] = (k == 0) ? 1.0f : 0.0f;  // identity, rotated layout
    int ilog = 0;
    float T = 1.0f;

    const float4* ob4 = (const float4*)(obvs + (long)b * NS) + c * M4;
    float4 xv = ob4[0];
    for (int m = 0; m < M4; ++m) {
        float4 xnext = ob4[(m + 1) & (M4 - 1)];
        if (m | c) T = step2(W, T, xv.x, A2, B2, C2);   // chunk 0 skips t=0 (epilogue init)
        T = step2(W, T, xv.y, A2, B2, C2);
        T = step2(W, T, xv.z, A2, B2, C2);
        T = step2(W, T, xv.w, A2, B2, C2);
        // branchless renorm: T = 2^E*mant -> scale W,T by 2^-E, ilog += E.
        // te==0 guard: never rescale a denormal/zero T (prevents runaway).
        int te = (__float_as_int(T) >> 23) & 255;
        int ok = (te != 0);
        float s = ok ? __int_as_float((254 - te) << 23) : 1.0f;
        ilog += ok ? (te - 127) : 0;
#pragma unroll
        for (int k = 0; k < 16; ++k) W[k] *= s;
        T *= s;
        xv = xnext;
    }

    int sid[16];
    sid[0] = r;
    sid[1]  = rotk<1>(r);   sid[2]  = rotk<2>(r);   sid[3]  = rotk<3>(r);
    sid[4]  = rotk<4>(r);   sid[5]  = rotk<5>(r);   sid[6]  = rotk<6>(r);
    sid[7]  = rotk<7>(r);   sid[8]  = rotk<8>(r);   sid[9]  = rotk<9>(r);
    sid[10] = rotk<10>(r);  sid[11] = rotk<11>(r);  sid[12] = rotk<12>(r);
    sid[13] = rotk<13>(r);  sid[14] = rotk<14>(r);  sid[15] = rotk<15>(r);

    float lg = (float)ilog + flog2(T);     // true column log2-sum (T in [1,2))
    float mx = gmax16(lg);                 // chunk max over 16 columns
    float sc = fexp2((float)ilog - mx);    // scale so chunk max colsum = 1
    float* dst = wsW + (long)g * 256 + r;  // M[j][r] at j*16+r (fp32)
#pragma unroll
    for (int k = 0; k < 16; ++k) dst[sid[k] * 16] = W[k] * sc;
    if (r == 0) wsM[g] = mx;
}

// P = Mb * Ma, one product per wave (round-6-proven).
__device__ __forceinline__ void mat16_mul(float* dR, float* dT,
                                          const float* MbR, const float* MaT,
                                          int lane) {
    int a = lane >> 3;
    int cc = lane & 7;
    float b0[16], b1[16], a0[16], a1[16];
    const float4* pb0 = (const float4*)(MbR + (2 * a) * ROWS);
    const float4* pb1 = (const float4*)(MbR + (2 * a + 1) * ROWS);
    const float4* pa0 = (const float4*)(MaT + (2 * cc) * ROWS);
    const float4* pa1 = (const float4*)(MaT + (2 * cc + 1) * ROWS);
#pragma unroll
    for (int q = 0; q < 4; ++q) {
        *(float4*)&b0[4 * q] = pb0[q];
        *(float4*)&b1[4 * q] = pb1[q];
        *(float4*)&a0[4 * q] = pa0[q];
        *(float4*)&a1[4 * q] = pa1[q];
    }
    float c00 = 0.f, c01 = 0.f, c10 = 0.f, c11 = 0.f;
#pragma unroll
    for (int k = 0; k < 16; ++k) {
        c00 = fmaf(b0[k], a0[k], c00);
        c01 = fmaf(b0[k], a1[k], c01);
        c10 = fmaf(b1[k], a0[k], c10);
        c11 = fmaf(b1[k], a1[k], c11);
    }
    *(float2*)(dR + (2 * a) * ROWS + 2 * cc)     = make_float2(c00, c01);
    *(float2*)(dR + (2 * a + 1) * ROWS + 2 * cc) = make_float2(c10, c11);
    if (dT) {
        *(float2*)(dT + (2 * cc) * ROWS + 2 * a)     = make_float2(c00, c10);
        *(float2*)(dT + (2 * cc + 1) * ROWS + 2 * a) = make_float2(c01, c11);
    }
}

// Phase 2+3: VERBATIM round-6-passed structure as a standalone kernel.
// One block per b: 8 rounds of (stage 8 fp32 mats -> tree 8->1), final tree
// 8->1, init-vector apply + logsumexp + atomicAdd.
__global__ __launch_bounds__(256, 2) void hmm_phase23(const float* __restrict__ obvs,
                                                      const float* __restrict__ mu,
                                                      const float* __restrict__ log_sigma,
                                                      const float* __restrict__ prior_logits,
                                                      const float* __restrict__ wsW,
                                                      const float* __restrict__ wsM,
                                                      float* __restrict__ out) {
    __shared__ float smem[12800];   // 51,200 B: stage(8x640) + scr(8x640) + resB(8x320)
    float* stage = smem;
    float* scr   = smem + 5120;
    float* resB  = smem + 10240;

    int bb = blockIdx.x;
    int tid = threadIdx.x;
    int wid = tid >> 6;
    int lane = tid & 63;

    for (int rd = 0; rd < 8; ++rd) {
        const float4* src = (const float4*)(wsW + ((long)bb * NC + rd * 8) * 256);
        __syncthreads();                   // stage reuse vs previous round's reads
#pragma unroll
        for (int q = 0; q < 2; ++q) {
            int f = tid + q * 256;
            float4 v = src[f];
            int m = f >> 6, idx = f & 63, j = idx >> 2, kq = idx & 3;
            *(float4*)(stage + m * UNIT + j * ROWS + kq * 4) = v;
            float* Tb = stage + m * UNIT + SLOT;
            Tb[(4 * kq + 0) * ROWS + j] = v.x;
            Tb[(4 * kq + 1) * ROWS + j] = v.y;
            Tb[(4 * kq + 2) * ROWS + j] = v.z;
            Tb[(4 * kq + 3) * ROWS + j] = v.w;
        }
        __syncthreads();
        // in-round tree 8 -> 4 -> 2 -> 1  (later * earlier)
        if (wid < 4)
            mat16_mul(scr + wid * UNIT, scr + wid * UNIT + SLOT,
                      stage + (2 * wid + 1) * UNIT, stage + (2 * wid) * UNIT + SLOT, lane);
        __syncthreads();
        if (wid < 2)
            mat16_mul(scr + (4 + wid) * UNIT, scr + (4 + wid) * UNIT + SLOT,
                      scr + (2 * wid + 1) * UNIT, scr + (2 * wid) * UNIT + SLOT, lane);
        __syncthreads();
        if (wid == 0)
            mat16_mul(resB + rd * SLOT, nullptr,
                      scr + 5 * UNIT, scr + 4 * UNIT + SLOT, lane);
    }
    __syncthreads();

    // transposes of the 8 round-results into stage
    for (int e = tid; e < 8 * 256; e += 256) {
        int m = e >> 8, idx = e & 255, j = idx >> 4, r = idx & 15;
        stage[m * SLOT + r * ROWS + j] = resB[m * SLOT + j * ROWS + r];
    }
    __syncthreads();

    // final tree 8 -> 4 -> 2 -> 1
    for (int i = wid; i < 4; i += 4)
        mat16_mul(scr + i * UNIT, scr + i * UNIT + SLOT,
                  resB + (2 * i + 1) * SLOT, stage + (2 * i) * SLOT, lane);
    __syncthreads();
    float* cur = scr;
    float* oth = stage;
    int n = 4;
    while (n > 1) {
        n >>= 1;
        for (int i = wid; i < n; i += 4)
            mat16_mul(oth + i * UNIT, oth + i * UNIT + SLOT,
                      cur + (2 * i + 1) * UNIT, cur + (2 * i) * UNIT + SLOT, lane);
        __syncthreads();
        float* t = cur; cur = oth; oth = t;
    }
    // final combined matrix rows at cur[j*ROWS + k]

    if (tid < 16) {
        int jj = tid;
        float ls = log_sigma[jj];
        float mk = mu[jj];
        float iv = fexp2(-2.0f * LOG2E * ls);
        float A2 = -0.5f * LOG2E * iv;
        float B2 = LOG2E * mk * iv;
        float C2 = LOG2E * (-0.5f * mk * mk * iv - ls - HLOG2PI);
        float x = obvs[(long)bb * NS];                   // t = 0
        float e = fexp2(LOG2E * prior_logits[jj]);
        float Z = gsum16(e);
        float p0 = fexp2(fmaf(x, fmaf(x, A2, B2), C2)) * e;
        const float* Mrow = cur + jj * ROWS;
        float mr[16];
        *(float4*)&mr[0]  = ((const float4*)Mrow)[0];
        *(float4*)&mr[4]  = ((const float4*)Mrow)[1];
        *(float4*)&mr[8]  = ((const float4*)Mrow)[2];
        *(float4*)&mr[12] = ((const float4*)Mrow)[3];
        float q = 0.0f;
#pragma unroll
        for (int rr = 0; rr < 16; ++rr) q = fmaf(mr[rr], __shfl(p0, rr, 16), q);
        float Tq = gsum16(q);
        const float* pm = wsM + bb * NC + jj * 4;
        float msum = gsum16(pm[0] + pm[1] + pm[2] + pm[3]);
        if (jj == 0) {
            float res = (flog2(Tq) - flog2(Z) + msum) * LN2;
            atomicAdd(out, res);
        }
    }
}

extern "C" void kernel_launch(void* const* d_in, const int* in_sizes, int n_in,
                              void* d_out, int out_size, void* d_ws, size_t ws_size,
                              hipStream_t stream) {
    const float* obvs = (const float*)d_in[0];
    const float* mu = (const float*)d_in[1];
    const float* log_sigma = (const float*)d_in[2];
    const float* prior_logits = (const float*)d_in[3];
    float* out = (float*)d_out;

    float* wsW = (float*)d_ws;                          // NB*NC*256 floats = 8.39 MB
    float* wsM = wsW + (size_t)NB * NC * 256;           // 8192 floats

    hmm_phase1<<<dim3(NB * NC * 16 / 256), dim3(256), 0, stream>>>(obvs, mu, log_sigma,
                                                                   wsW, wsM, out);
    hmm_phase23<<<dim3(NB), dim3(256), 0, stream>>>(obvs, mu, log_sigma, prior_logits,
                                                    wsW, wsM, out);
}

// Round 9
// 109.341 us; speedup vs baseline: 1.5269x; 1.0735x over previous
//
#include <hip/hip_runtime.h>

#define NB 128
#define NS 8192
#define NC 64
#define NL (NS / NC)          // 128 steps per chunk
#define M4 (NL / 4)           // 32 float4 groups

#define LOG2E 1.4426950408889634f
#define HLOG2PI 0.918938533204672742f
#define LN2 0.69314718055994531f

// phase23 LDS layout (round-6/8-proven)
#define ROWS 20          // padded leading dim
#define UNIT 640         // dual unit: R[16x20] + T[16x20]
#define SLOT 320

typedef float v2f __attribute__((ext_vector_type(2)));

__device__ __forceinline__ float fexp2(float x) { return __builtin_amdgcn_exp2f(x); }
__device__ __forceinline__ float flog2(float x) { return __builtin_amdgcn_logf(x); }

__device__ __forceinline__ float gsum16(float v) {
    v += __shfl_xor(v, 1, 16);
    v += __shfl_xor(v, 2, 16);
    v += __shfl_xor(v, 4, 16);
    v += __shfl_xor(v, 8, 16);
    return v;
}
__device__ __forceinline__ float gmax16(float v) {
    v = fmaxf(v, __shfl_xor(v, 1, 16));
    v = fmaxf(v, __shfl_xor(v, 2, 16));
    v = fmaxf(v, __shfl_xor(v, 4, 16));
    v = fmaxf(v, __shfl_xor(v, 8, 16));
    return v;
}

template <int K>
__device__ __forceinline__ int rotk(int x) {
    return __builtin_amdgcn_mov_dpp(x, 0x120 + K, 0xF, 0xF, false);
}

// One HMM step, rotated-W layout, PACKED fp32 (v_pk_fma/v_pk_mul/v_pk_add):
// W pairs Wv[i] = (W[2i], W[2i+1]); lik pairs gathered by DPP into pair regs.
// Takes current colsum T, returns new colsum. Bit-identical math to round 8.
__device__ __forceinline__ float step2(v2f (&Wv)[8], float T, float xx,
                                       float A2, float B2, float C2) {
    const float amb = 0.9f - 0.1f / 15.0f;
    const float bco = 0.1f / 15.0f;
    float myl = fexp2(fmaf(xx, fmaf(xx, A2, B2), C2));   // ONE exp per lane
    int mi = __float_as_int(myl);
    float bT = bco * T;
    v2f bT2 = {bT, bT};
    v2f amb2 = {amb, amb};
    v2f L0 = {myl,                              __int_as_float(rotk<1>(mi))};
    v2f L1 = {__int_as_float(rotk<2>(mi)),  __int_as_float(rotk<3>(mi))};
    v2f L2 = {__int_as_float(rotk<4>(mi)),  __int_as_float(rotk<5>(mi))};
    v2f L3 = {__int_as_float(rotk<6>(mi)),  __int_as_float(rotk<7>(mi))};
    v2f L4 = {__int_as_float(rotk<8>(mi)),  __int_as_float(rotk<9>(mi))};
    v2f L5 = {__int_as_float(rotk<10>(mi)), __int_as_float(rotk<11>(mi))};
    v2f L6 = {__int_as_float(rotk<12>(mi)), __int_as_float(rotk<13>(mi))};
    v2f L7 = {__int_as_float(rotk<14>(mi)), __int_as_float(rotk<15>(mi))};
    Wv[0] = __builtin_elementwise_fma(amb2, Wv[0], bT2) * L0;
    Wv[1] = __builtin_elementwise_fma(amb2, Wv[1], bT2) * L1;
    Wv[2] = __builtin_elementwise_fma(amb2, Wv[2], bT2) * L2;
    Wv[3] = __builtin_elementwise_fma(amb2, Wv[3], bT2) * L3;
    Wv[4] = __builtin_elementwise_fma(amb2, Wv[4], bT2) * L4;
    Wv[5] = __builtin_elementwise_fma(amb2, Wv[5], bT2) * L5;
    Wv[6] = __builtin_elementwise_fma(amb2, Wv[6], bT2) * L6;
    Wv[7] = __builtin_elementwise_fma(amb2, Wv[7], bT2) * L7;
    v2f s = ((Wv[0] + Wv[1]) + (Wv[2] + Wv[3])) + ((Wv[4] + Wv[5]) + (Wv[6] + Wv[7]));
    return s.x + s.y;
}

// Phase 1: thread (b, chunk c, column r) evolves basis e_r through its chunk.
// Round-8 skeleton (nc=64, fp32 store, per-4-step guarded exponent renorm);
// packed-math inner loop; branch peeled out of the hot loop;
// __launch_bounds__(256,2): 256-VGPR budget at the real 2-wave/SIMD occupancy.
__global__ __launch_bounds__(256, 2) void hmm_phase1(const float* __restrict__ obvs,
                                                     const float* __restrict__ mu,
                                                     const float* __restrict__ log_sigma,
                                                     float* __restrict__ wsW,
                                                     float* __restrict__ wsM,
                                                     float* __restrict__ out) {
    int tid = blockIdx.x * blockDim.x + threadIdx.x;
    if (tid == 0) out[0] = 0.0f;           // phase23 atomicAdds after this dispatch
    int r = tid & 15;
    int g = tid >> 4;                      // g = b*NC + c
    int b = g >> 6;
    int c = g & (NC - 1);

    float ls = log_sigma[r];
    float mk = mu[r];
    float iv = fexp2(-2.0f * LOG2E * ls);
    float A2 = -0.5f * LOG2E * iv;
    float B2 = LOG2E * mk * iv;
    float C2 = LOG2E * (-0.5f * mk * mk * iv - ls - HLOG2PI);

    v2f Wv[8];
#pragma unroll
    for (int i = 0; i < 8; ++i) Wv[i] = (v2f){0.0f, 0.0f};
    Wv[0].x = 1.0f;                        // identity in rotated layout
    int ilog = 0;
    float T = 1.0f;

    const float4* ob4 = (const float4*)(obvs + (long)b * NS) + c * M4;
    float4 xv = ob4[0];
    float4 xn = ob4[1];
    // peeled m=0 group: chunk 0 skips t=0 (handled as init vector in phase23)
    if (c) T = step2(Wv, T, xv.x, A2, B2, C2);
    T = step2(Wv, T, xv.y, A2, B2, C2);
    T = step2(Wv, T, xv.z, A2, B2, C2);
    T = step2(Wv, T, xv.w, A2, B2, C2);
    {
        int te = (__float_as_int(T) >> 23) & 255;
        int ok = (te != 0);
        float s = ok ? __int_as_float((254 - te) << 23) : 1.0f;
        ilog += ok ? (te - 127) : 0;
        v2f s2 = {s, s};
#pragma unroll
        for (int i = 0; i < 8; ++i) Wv[i] *= s2;
        T *= s;
    }
    xv = xn;
    for (int m = 1; m < M4; ++m) {
        xn = ob4[(m + 1) < M4 ? (m + 1) : m];
        T = step2(Wv, T, xv.x, A2, B2, C2);
        T = step2(Wv, T, xv.y, A2, B2, C2);
        T = step2(Wv, T, xv.z, A2, B2, C2);
        T = step2(Wv, T, xv.w, A2, B2, C2);
        // guarded branchless exponent renorm (round-8-proven)
        int te = (__float_as_int(T) >> 23) & 255;
        int ok = (te != 0);
        float s = ok ? __int_as_float((254 - te) << 23) : 1.0f;
        ilog += ok ? (te - 127) : 0;
        v2f s2 = {s, s};
#pragma unroll
        for (int i = 0; i < 8; ++i) Wv[i] *= s2;
        T *= s;
        xv = xn;
    }

    int sid[16];
    sid[0] = r;
    sid[1]  = rotk<1>(r);   sid[2]  = rotk<2>(r);   sid[3]  = rotk<3>(r);
    sid[4]  = rotk<4>(r);   sid[5]  = rotk<5>(r);   sid[6]  = rotk<6>(r);
    sid[7]  = rotk<7>(r);   sid[8]  = rotk<8>(r);   sid[9]  = rotk<9>(r);
    sid[10] = rotk<10>(r);  sid[11] = rotk<11>(r);  sid[12] = rotk<12>(r);
    sid[13] = rotk<13>(r);  sid[14] = rotk<14>(r);  sid[15] = rotk<15>(r);

    float lg = (float)ilog + flog2(T);     // true column log2-sum (T in [1,2))
    float mx = gmax16(lg);                 // chunk max over 16 columns
    float sc = fexp2((float)ilog - mx);    // scale so chunk max colsum = 1
    float* dst = wsW + (long)g * 256 + r;  // M[j][r] at j*16+r (fp32)
#pragma unroll
    for (int i = 0; i < 8; ++i) {
        dst[sid[2 * i] * 16]     = Wv[i].x * sc;
        dst[sid[2 * i + 1] * 16] = Wv[i].y * sc;
    }
    if (r == 0) wsM[g] = mx;
}

// P = Mb * Ma, one product per wave (round-6/8-proven).
__device__ __forceinline__ void mat16_mul(float* dR, float* dT,
                                          const float* MbR, const float* MaT,
                                          int lane) {
    int a = lane >> 3;
    int cc = lane & 7;
    float b0[16], b1[16], a0[16], a1[16];
    const float4* pb0 = (const float4*)(MbR + (2 * a) * ROWS);
    const float4* pb1 = (const float4*)(MbR + (2 * a + 1) * ROWS);
    const float4* pa0 = (const float4*)(MaT + (2 * cc) * ROWS);
    const float4* pa1 = (const float4*)(MaT + (2 * cc + 1) * ROWS);
#pragma unroll
    for (int q = 0; q < 4; ++q) {
        *(float4*)&b0[4 * q] = pb0[q];
        *(float4*)&b1[4 * q] = pb1[q];
        *(float4*)&a0[4 * q] = pa0[q];
        *(float4*)&a1[4 * q] = pa1[q];
    }
    float c00 = 0.f, c01 = 0.f, c10 = 0.f, c11 = 0.f;
#pragma unroll
    for (int k = 0; k < 16; ++k) {
        c00 = fmaf(b0[k], a0[k], c00);
        c01 = fmaf(b0[k], a1[k], c01);
        c10 = fmaf(b1[k], a0[k], c10);
        c11 = fmaf(b1[k], a1[k], c11);
    }
    *(float2*)(dR + (2 * a) * ROWS + 2 * cc)     = make_float2(c00, c01);
    *(float2*)(dR + (2 * a + 1) * ROWS + 2 * cc) = make_float2(c10, c11);
    if (dT) {
        *(float2*)(dT + (2 * cc) * ROWS + 2 * a)     = make_float2(c00, c10);
        *(float2*)(dT + (2 * cc + 1) * ROWS + 2 * a) = make_float2(c01, c11);
    }
}

// Phase 2+3: VERBATIM round-8-passed kernel.
__global__ __launch_bounds__(256, 2) void hmm_phase23(const float* __restrict__ obvs,
                                                      const float* __restrict__ mu,
                                                      const float* __restrict__ log_sigma,
                                                      const float* __restrict__ prior_logits,
                                                      const float* __restrict__ wsW,
                                                      const float* __restrict__ wsM,
                                                      float* __restrict__ out) {
    __shared__ float smem[12800];   // 51,200 B: stage(8x640) + scr(8x640) + resB(8x320)
    float* stage = smem;
    float* scr   = smem + 5120;
    float* resB  = smem + 10240;

    int bb = blockIdx.x;
    int tid = threadIdx.x;
    int wid = tid >> 6;
    int lane = tid & 63;

    for (int rd = 0; rd < 8; ++rd) {
        const float4* src = (const float4*)(wsW + ((long)bb * NC + rd * 8) * 256);
        __syncthreads();                   // stage reuse vs previous round's reads
#pragma unroll
        for (int q = 0; q < 2; ++q) {
            int f = tid + q * 256;
            float4 v = src[f];
            int m = f >> 6, idx = f & 63, j = idx >> 2, kq = idx & 3;
            *(float4*)(stage + m * UNIT + j * ROWS + kq * 4) = v;
            float* Tb = stage + m * UNIT + SLOT;
            Tb[(4 * kq + 0) * ROWS + j] = v.x;
            Tb[(4 * kq + 1) * ROWS + j] = v.y;
            Tb[(4 * kq + 2) * ROWS + j] = v.z;
            Tb[(4 * kq + 3) * ROWS + j] = v.w;
        }
        __syncthreads();
        // in-round tree 8 -> 4 -> 2 -> 1  (later * earlier)
        if (wid < 4)
            mat16_mul(scr + wid * UNIT, scr + wid * UNIT + SLOT,
                      stage + (2 * wid + 1) * UNIT, stage + (2 * wid) * UNIT + SLOT, lane);
        __syncthreads();
        if (wid < 2)
            mat16_mul(scr + (4 + wid) * UNIT, scr + (4 + wid) * UNIT + SLOT,
                      scr + (2 * wid + 1) * UNIT, scr + (2 * wid) * UNIT + SLOT, lane);
        __syncthreads();
        if (wid == 0)
            mat16_mul(resB + rd * SLOT, nullptr,
                      scr + 5 * UNIT, scr + 4 * UNIT + SLOT, lane);
    }
    __syncthreads();

    // transposes of the 8 round-results into stage
    for (int e = tid; e < 8 * 256; e += 256) {
        int m = e >> 8, idx = e & 255, j = idx >> 4, r = idx & 15;
        stage[m * SLOT + r * ROWS + j] = resB[m * SLOT + j * ROWS + r];
    }
    __syncthreads();

    // final tree 8 -> 4 -> 2 -> 1
    for (int i = wid; i < 4; i += 4)
        mat16_mul(scr + i * UNIT, scr + i * UNIT + SLOT,
                  resB + (2 * i + 1) * SLOT, stage + (2 * i) * SLOT, lane);
    __syncthreads();
    float* cur = scr;
    float* oth = stage;
    int n = 4;
    while (n > 1) {
        n >>= 1;
        for (int i = wid; i < n; i += 4)
            mat16_mul(oth + i * UNIT, oth + i * UNIT + SLOT,
                      cur + (2 * i + 1) * UNIT, cur + (2 * i) * UNIT + SLOT, lane);
        __syncthreads();
        float* t = cur; cur = oth; oth = t;
    }
    // final combined matrix rows at cur[j*ROWS + k]

    if (tid < 16) {
        int jj = tid;
        float ls = log_sigma[jj];
        float mk = mu[jj];
        float iv = fexp2(-2.0f * LOG2E * ls);
        float A2 = -0.5f * LOG2E * iv;
        float B2 = LOG2E * mk * iv;
        float C2 = LOG2E * (-0.5f * mk * mk * iv - ls - HLOG2PI);
        float x = obvs[(long)bb * NS];                   // t = 0
        float e = fexp2(LOG2E * prior_logits[jj]);
        float Z = gsum16(e);
        float p0 = fexp2(fmaf(x, fmaf(x, A2, B2), C2)) * e;
        const float* Mrow = cur + jj * ROWS;
        float mr[16];
        *(float4*)&mr[0]  = ((const float4*)Mrow)[0];
        *(float4*)&mr[4]  = ((const float4*)Mrow)[1];
        *(float4*)&mr[8]  = ((const float4*)Mrow)[2];
        *(float4*)&mr[12] = ((const float4*)Mrow)[3];
        float q = 0.0f;
#pragma unroll
        for (int rr = 0; rr < 16; ++rr) q = fmaf(mr[rr], __shfl(p0, rr, 16), q);
        float Tq = gsum16(q);
        const float* pm = wsM + bb * NC + jj * 4;
        float msum = gsum16(pm[0] + pm[1] + pm[2] + pm[3]);
        if (jj == 0) {
            float res = (flog2(Tq) - flog2(Z) + msum) * LN2;
            atomicAdd(out, res);
        }
    }
}

extern "C" void kernel_launch(void* const* d_in, const int* in_sizes, int n_in,
                              void* d_out, int out_size, void* d_ws, size_t ws_size,
                              hipStream_t stream) {
    const float* obvs = (const float*)d_in[0];
    const float* mu = (const float*)d_in[1];
    const float* log_sigma = (const float*)d_in[2];
    const float* prior_logits = (const float*)d_in[3];
    float* out = (float*)d_out;

    float* wsW = (float*)d_ws;                          // NB*NC*256 floats = 8.39 MB
    float* wsM = wsW + (size_t)NB * NC * 256;           // 8192 floats

    hmm_phase1<<<dim3(NB * NC * 16 / 256), dim3(256), 0, stream>>>(obvs, mu, log_sigma,
                                                                   wsW, wsM, out);
    hmm_phase23<<<dim3(NB), dim3(256), 0, stream>>>(obvs, mu, log_sigma, prior_logits,
                                                    wsW, wsM, out);
}